// Round 4
// baseline (147.576 us; speedup 1.0000x reference)
//
#include <hip/hip_runtime.h>
#include <cstddef>

#define B_    4
#define CIN_  256
#define COUT_ 256
#define H_    64
#define W_    64
#define KK_   9
#define G_    4
#define PAD_  1
#define TPX   64          // pixels per block = one full W row
#define NSTEP 36          // 4 groups * 9 taps, K=64 each

typedef short bf16x8 __attribute__((ext_vector_type(8)));
typedef float f32x4  __attribute__((ext_vector_type(4)));
typedef __attribute__((address_space(1))) const unsigned int* gptr_t;
typedef __attribute__((address_space(3))) unsigned int*       lptr_t;

// fp32 -> bf16 round-to-nearest-even
__device__ __forceinline__ unsigned short f2bf(float v) {
    unsigned int u = __float_as_uint(v);
    u += 0x7fffu + ((u >> 16) & 1u);
    return (unsigned short)(u >> 16);
}
__device__ __forceinline__ float f_lo(unsigned int u) { return __uint_as_float(u << 16); }
__device__ __forceinline__ float f_hi(unsigned int u) { return __uint_as_float(u & 0xffff0000u); }

// xT[b][h][w][c] (bf16, NHWC) <- x[b][c][h][w] (fp32). Block: (b,h,chalf) = 128 ch x 64 w.
__global__ __launch_bounds__(256) void xt_kernel(const float* __restrict__ x,
                                                 unsigned short* __restrict__ xT) {
    __shared__ unsigned short s[128][66];
    const int tid   = threadIdx.x;
    const int bh    = blockIdx.x >> 1;          // b*64 + h
    const int chalf = blockIdx.x & 1;
    const size_t src_base = ((size_t)(bh >> 6) * CIN_ + chalf * 128) * (H_ * W_) + (bh & 63) * W_;
    #pragma unroll 4
    for (int k = 0; k < 32; ++k) {
        int i = k * 256 + tid;
        int c = i >> 6, w = i & 63;
        s[c][w] = f2bf(x[src_base + (size_t)c * (H_ * W_) + w]);
    }
    __syncthreads();
    #pragma unroll 4
    for (int k = 0; k < 16; ++k) {
        int j  = k * 256 + tid;
        int c2 = (j & 63) * 2, w = j >> 6;
        unsigned int lo = s[c2][w], hi = s[c2 + 1][w];
        *(unsigned int*)(xT + ((size_t)bh * 64 + w) * 256 + chalf * 128 + c2) = lo | (hi << 16);
    }
}

// wb: 36 tiles [g][kk] of [o][pos*8+e] bf16, pos = j ^ (o&7), c = g*64 + j*8 + e
__global__ __launch_bounds__(256) void wt_kernel(const float* __restrict__ w,
                                                 unsigned short* __restrict__ wb) {
    int idx = blockIdx.x * 256 + threadIdx.x;    // 36*16384 exactly
    int e   = idx & 7;
    int pos = (idx >> 3) & 7;
    int o   = (idx >> 6) & 255;
    int t   = idx >> 14;                         // g*9 + kk
    int g   = t / 9, kk = t - g * 9;
    int j   = pos ^ (o & 7);
    int c   = g * 64 + j * 8 + e;
    wb[idx] = f2bf(w[(o * CIN_ + c) * KK_ + kk]);
}

__global__ __launch_bounds__(512, 2) void dcn_kernel(
    const unsigned short* __restrict__ xT, const float* __restrict__ y,
    const float* __restrict__ w_off, const unsigned short* __restrict__ wb,
    float* __restrict__ out)
{
    __shared__ unsigned short s_W[2][COUT_ * 64];   // 2 x 32 KB (dbuf)
    __shared__ unsigned short s_S[2][TPX * 64];     // 2 x  8 KB (dbuf)

    const int tid = threadIdx.x;
    // XCD swizzle: co-resident blocks share b and a contiguous h range
    const int bid = blockIdx.x;                 // 256 blocks = 1/CU
    const int xcd = bid & 7, loc = bid >> 3;
    const int b   = xcd >> 1;
    const int h   = (xcd & 1) * 32 + loc;

    // sampling mapping: thread -> (pixel sp, 8-ch chunk c8); exactly 64*8 = 512 items
    const int sp = tid & 63;
    const int c8 = tid >> 6;

    // per-thread y values for its pixel (offsets computed on the fly per step)
    const float yv0 = y[((b * 2 + 0) * H_ + h) * W_ + sp];
    const float yv1 = y[((b * 2 + 1) * H_ + h) * W_ + sp];

    // mfma mapping: wave -> 32 px (pg) x 64 outs (oh)
    const int lane = tid & 63, wave = tid >> 6;
    const int pg  = wave & 1, oh = wave >> 1;
    const int l15 = lane & 15, kq = lane >> 4, sw = l15 & 7;

    f32x4 acc[8];   // [nt][mt] : 2 px-subtiles x 4 out-subtiles
    #pragma unroll
    for (int i = 0; i < 8; ++i) acc[i] = (f32x4){0.f, 0.f, 0.f, 0.f};

    const size_t xbase = (size_t)b * (H_ * W_ * 256) + c8 * 8;

    // ---------------- helpers (lambdas keep register state local) ----------------
    auto dma_w = [&](int s, int buf) {
        const unsigned short* src = wb + (size_t)s * 16384;
        unsigned short* dst = &s_W[buf][0];
        #pragma unroll
        for (int j = 0; j < 4; ++j) {
            const int off = (j * 512 + tid) * 8;       // ushort idx, 16 B per thread
            __builtin_amdgcn_global_load_lds((gptr_t)(src + off),
                                             (lptr_t)(dst + off), 16, 0, 0);
        }
    };

    auto sample = [&](int s, int buf) {
        const int g  = s / 9;
        const int kk = s - g * 9;
        const float4 co = *(const float4*)(w_off + s * 4);   // uniform scalar load
        const float dy = fmaf(yv0, co.x, yv1 * co.y);
        const float dx = fmaf(yv0, co.z, yv1 * co.w);
        const float yc = (float)(h + (kk / 3) - PAD_) + dy;
        const float xc = (float)(sp + (kk % 3) - PAD_) + dx;
        const float yf = floorf(yc), xf = floorf(xc);
        const float wy = yc - yf,    wx = xc - xf;
        const int   yi = (int)yf,    xi = (int)xf;
        float w00 = (1.f - wy) * (1.f - wx);
        float w01 = (1.f - wy) * wx;
        float w10 = wy * (1.f - wx);
        float w11 = wy * wx;
        const bool y0ok = (yi >= 0) & (yi < H_);
        const bool y1ok = (yi >= -1) & (yi < H_ - 1);
        const bool x0ok = (xi >= 0) & (xi < W_);
        const bool x1ok = (xi >= -1) & (xi < W_ - 1);
        w00 = (y0ok & x0ok) ? w00 : 0.f;
        w01 = (y0ok & x1ok) ? w01 : 0.f;
        w10 = (y1ok & x0ok) ? w10 : 0.f;
        w11 = (y1ok & x1ok) ? w11 : 0.f;
        const int y0c = min(max(yi, 0), H_ - 1);
        const int y1c = min(max(yi + 1, 0), H_ - 1);
        const int x0c = min(max(xi, 0), W_ - 1);
        const int x1c = min(max(xi + 1, 0), W_ - 1);
        const unsigned short* xb = xT + xbase + g * 64;
        const uint4 A  = *(const uint4*)(xb + ((size_t)y0c * W_ + x0c) * 256);
        const uint4 Bv = *(const uint4*)(xb + ((size_t)y0c * W_ + x1c) * 256);
        const uint4 C  = *(const uint4*)(xb + ((size_t)y1c * W_ + x0c) * 256);
        const uint4 D  = *(const uint4*)(xb + ((size_t)y1c * W_ + x1c) * 256);
        const unsigned int av[4] = {A.x, A.y, A.z, A.w};
        const unsigned int bv[4] = {Bv.x, Bv.y, Bv.z, Bv.w};
        const unsigned int cv[4] = {C.x, C.y, C.z, C.w};
        const unsigned int dv[4] = {D.x, D.y, D.z, D.w};
        unsigned int res[4];
        #pragma unroll
        for (int q = 0; q < 4; ++q) {
            float rl = w00 * f_lo(av[q]);
            rl = fmaf(w01, f_lo(bv[q]), rl);
            rl = fmaf(w10, f_lo(cv[q]), rl);
            rl = fmaf(w11, f_lo(dv[q]), rl);
            float rh = w00 * f_hi(av[q]);
            rh = fmaf(w01, f_hi(bv[q]), rh);
            rh = fmaf(w10, f_hi(cv[q]), rh);
            rh = fmaf(w11, f_hi(dv[q]), rh);
            res[q] = __builtin_amdgcn_perm(__float_as_uint(rh),
                                           __float_as_uint(rl), 0x07060302u);
        }
        *(uint4*)(&s_S[buf][0] + sp * 64 + ((c8 ^ (sp & 7)) * 8)) =
            make_uint4(res[0], res[1], res[2], res[3]);
    };

    // ---------------- software-pipelined main loop ----------------
    dma_w(0, 0);
    sample(0, 0);
    __syncthreads();

    for (int s = 0; s < NSTEP; ++s) {
        const int cur = s & 1;
        if (s < NSTEP - 1) {
            dma_w(s + 1, cur ^ 1);
            sample(s + 1, cur ^ 1);
        }
        // MFMA on buffer `cur` (its DMA/stores were fenced by the previous barrier)
        const unsigned short* Wb = &s_W[cur][0];
        const unsigned short* Sb = &s_S[cur][0];
        #pragma unroll
        for (int kh = 0; kh < 2; ++kh) {
            const int pos = ((kh * 4 + kq) ^ sw) * 8;
            #pragma unroll
            for (int nt = 0; nt < 2; ++nt) {
                const bf16x8 bfrag = *(const bf16x8*)(Sb + (pg * 32 + nt * 16 + l15) * 64 + pos);
                #pragma unroll
                for (int mt = 0; mt < 4; ++mt) {
                    const bf16x8 afrag = *(const bf16x8*)(Wb + (oh * 64 + mt * 16 + l15) * 64 + pos);
                    acc[nt * 4 + mt] =
                        __builtin_amdgcn_mfma_f32_16x16x32_bf16(afrag, bfrag, acc[nt * 4 + mt], 0, 0, 0);
                }
            }
        }
        __syncthreads();   // fences next buffer's DMA+stores; frees `cur` for overwrite
    }

    // ---- epilogue: ReLU + store. C/D: col=lane&15 -> px, row=(lane>>4)*4+r -> o ----
    #pragma unroll
    for (int nt = 0; nt < 2; ++nt) {
        const int px = pg * 32 + nt * 16 + l15;
        #pragma unroll
        for (int mt = 0; mt < 4; ++mt) {
            const int obase = oh * 64 + mt * 16 + kq * 4;
            #pragma unroll
            for (int r = 0; r < 4; ++r) {
                out[(((size_t)b * COUT_ + obase + r) * H_ + h) * W_ + px] =
                    fmaxf(acc[nt * 4 + mt][r], 0.f);
            }
        }
    }
}

extern "C" void kernel_launch(void* const* d_in, const int* in_sizes, int n_in,
                              void* d_out, int out_size, void* d_ws, size_t ws_size,
                              hipStream_t stream) {
    const float* x     = (const float*)d_in[0];
    const float* y     = (const float*)d_in[1];
    const float* w_off = (const float*)d_in[2];
    const float* w_def = (const float*)d_in[3];
    float* out = (float*)d_out;

    unsigned short* xT = (unsigned short*)d_ws;                 // 8 MB
    unsigned short* wb = (unsigned short*)d_ws + 4194304;       // 1.18 MB

    xt_kernel<<<B_ * H_ * 2, 256, 0, stream>>>(x, xT);
    wt_kernel<<<(NSTEP * 16384) / 256, 256, 0, stream>>>(w_def, wb);
    dcn_kernel<<<256, 512, 0, stream>>>(xT, y, w_off, wb, out);
}

// Round 5
// 140.699 us; speedup vs baseline: 1.0489x; 1.0489x over previous
//
#include <hip/hip_runtime.h>
#include <cstddef>

#define B_    4
#define CIN_  256
#define COUT_ 256
#define H_    64
#define W_    64
#define KK_   9
#define G_    4
#define PAD_  1
#define TP    32          // pixels per block
#define NSTEP 36          // 4 groups * 9 taps, K=64 each

typedef short bf16x8 __attribute__((ext_vector_type(8)));
typedef float f32x4  __attribute__((ext_vector_type(4)));
typedef __attribute__((address_space(1))) const unsigned int* gptr_t;
typedef __attribute__((address_space(3))) unsigned int*       lptr_t;

__device__ __forceinline__ unsigned short f2bf(float v) {
    unsigned int u = __float_as_uint(v);
    u += 0x7fffu + ((u >> 16) & 1u);
    return (unsigned short)(u >> 16);
}
__device__ __forceinline__ float f_lo(unsigned int u) { return __uint_as_float(u << 16); }
__device__ __forceinline__ float f_hi(unsigned int u) { return __uint_as_float(u & 0xffff0000u); }

// xT[b][h][w][c] (bf16, NHWC) <- x[b][c][h][w] (fp32)
__global__ __launch_bounds__(256) void xt_kernel(const float* __restrict__ x,
                                                 unsigned short* __restrict__ xT) {
    __shared__ unsigned short s[128][66];
    const int tid   = threadIdx.x;
    const int bh    = blockIdx.x >> 1;
    const int chalf = blockIdx.x & 1;
    const size_t src_base = ((size_t)(bh >> 6) * CIN_ + chalf * 128) * (H_ * W_) + (bh & 63) * W_;
    #pragma unroll 4
    for (int k = 0; k < 32; ++k) {
        int i = k * 256 + tid;
        int c = i >> 6, w = i & 63;
        s[c][w] = f2bf(x[src_base + (size_t)c * (H_ * W_) + w]);
    }
    __syncthreads();
    #pragma unroll 4
    for (int k = 0; k < 16; ++k) {
        int j  = k * 256 + tid;
        int c2 = (j & 63) * 2, w = j >> 6;
        unsigned int lo = s[c2][w], hi = s[c2 + 1][w];
        *(unsigned int*)(xT + ((size_t)bh * 64 + w) * 256 + chalf * 128 + c2) = lo | (hi << 16);
    }
}

// wb: 36 tiles [g][kk] of [o][pos*8+e] bf16, pos = j ^ (o&7), c = g*64 + j*8 + e
__global__ __launch_bounds__(256) void wt_kernel(const float* __restrict__ w,
                                                 unsigned short* __restrict__ wb) {
    int idx = blockIdx.x * 256 + threadIdx.x;    // 36*16384 exactly
    int e   = idx & 7;
    int pos = (idx >> 3) & 7;
    int o   = (idx >> 6) & 255;
    int t   = idx >> 14;                         // g*9 + kk
    int g   = t / 9, kk = t - g * 9;
    int j   = pos ^ (o & 7);
    int c   = g * 64 + j * 8 + e;
    wb[idx] = f2bf(w[(o * CIN_ + c) * KK_ + kk]);
}

struct SampRegs {
    uint4 A, Bv, C, D;
    float w00, w01, w10, w11;
};

__global__ __launch_bounds__(256, 2) void dcn_kernel(
    const unsigned short* __restrict__ xT, const float* __restrict__ y,
    const float* __restrict__ w_off, const unsigned short* __restrict__ wb,
    float* __restrict__ out)
{
    __shared__ unsigned short s_W[2][COUT_ * 64];   // 2 x 32 KB (dbuf)
    __shared__ unsigned short s_S[2][TP * 64];      // 2 x  4 KB (dbuf)

    const int tid = threadIdx.x;
    // XCD swizzle: co-resident blocks share b and an h half -> 1.1 MB x-slab + wb in L2
    const int bid = blockIdx.x;                 // 512 blocks = 2/CU
    const int xcd = bid & 7, loc = bid >> 3;    // loc in [0,64)
    const int b   = xcd >> 1;
    const int h   = (xcd & 1) * 32 + (loc >> 1);
    const int w0  = (loc & 1) * TP;

    // sampling mapping: thread -> (pixel sp, 8-ch chunk c8) ; 32*8 = 256 items
    const int sp = tid & 31;
    const int c8 = tid >> 5;

    const float yv0 = y[((b * 2 + 0) * H_ + h) * W_ + w0 + sp];
    const float yv1 = y[((b * 2 + 1) * H_ + h) * W_ + w0 + sp];

    // mfma mapping: 4 waves, wave oh covers 64 outs x all 32 px
    const int lane = tid & 63, oh = tid >> 6;
    const int l15  = lane & 15, kq = lane >> 4, sw = l15 & 7;

    f32x4 acc[8];   // [nt][mt] : 2 px-subtiles x 4 out-subtiles
    #pragma unroll
    for (int i = 0; i < 8; ++i) acc[i] = (f32x4){0.f, 0.f, 0.f, 0.f};

    const size_t xbase = (size_t)b * (H_ * W_ * 256) + c8 * 8;

    auto dma_w = [&](int s, int buf) {
        const unsigned short* src = wb + (size_t)s * 16384;
        unsigned short* dst = &s_W[buf][0];
        #pragma unroll
        for (int j = 0; j < 8; ++j) {
            const int off = (j * 256 + tid) * 8;       // 16 B per thread per pass
            __builtin_amdgcn_global_load_lds((gptr_t)(src + off),
                                             (lptr_t)(dst + off), 16, 0, 0);
        }
    };

    // phase 1: issue corner loads + compute weights (loads stay in flight)
    auto sample_load = [&](int s) -> SampRegs {
        SampRegs r;
        const int g  = s / 9;
        const int kk = s - g * 9;
        const float4 co = *(const float4*)(w_off + s * 4);   // uniform scalar load
        const float dy = fmaf(yv0, co.x, yv1 * co.y);
        const float dx = fmaf(yv0, co.z, yv1 * co.w);
        const float yc = (float)(h + (kk / 3) - PAD_) + dy;
        const float xc = (float)(w0 + sp + (kk % 3) - PAD_) + dx;
        const float yf = floorf(yc), xf = floorf(xc);
        const float wy = yc - yf,    wx = xc - xf;
        const int   yi = (int)yf,    xi = (int)xf;
        float w00 = (1.f - wy) * (1.f - wx);
        float w01 = (1.f - wy) * wx;
        float w10 = wy * (1.f - wx);
        float w11 = wy * wx;
        const bool y0ok = (yi >= 0) & (yi < H_);
        const bool y1ok = (yi >= -1) & (yi < H_ - 1);
        const bool x0ok = (xi >= 0) & (xi < W_);
        const bool x1ok = (xi >= -1) & (xi < W_ - 1);
        r.w00 = (y0ok & x0ok) ? w00 : 0.f;
        r.w01 = (y0ok & x1ok) ? w01 : 0.f;
        r.w10 = (y1ok & x0ok) ? w10 : 0.f;
        r.w11 = (y1ok & x1ok) ? w11 : 0.f;
        const int y0c = min(max(yi, 0), H_ - 1);
        const int y1c = min(max(yi + 1, 0), H_ - 1);
        const int x0c = min(max(xi, 0), W_ - 1);
        const int x1c = min(max(xi + 1, 0), W_ - 1);
        const unsigned short* xb = xT + xbase + g * 64;
        r.A  = *(const uint4*)(xb + ((size_t)y0c * W_ + x0c) * 256);
        r.Bv = *(const uint4*)(xb + ((size_t)y0c * W_ + x1c) * 256);
        r.C  = *(const uint4*)(xb + ((size_t)y1c * W_ + x0c) * 256);
        r.D  = *(const uint4*)(xb + ((size_t)y1c * W_ + x1c) * 256);
        return r;
    };

    // phase 2: bilinear combine + pack + LDS store
    auto sample_store = [&](const SampRegs& r, int buf) {
        const unsigned int av[4] = {r.A.x, r.A.y, r.A.z, r.A.w};
        const unsigned int bv[4] = {r.Bv.x, r.Bv.y, r.Bv.z, r.Bv.w};
        const unsigned int cv[4] = {r.C.x, r.C.y, r.C.z, r.C.w};
        const unsigned int dv[4] = {r.D.x, r.D.y, r.D.z, r.D.w};
        unsigned int res[4];
        #pragma unroll
        for (int q = 0; q < 4; ++q) {
            float rl = r.w00 * f_lo(av[q]);
            rl = fmaf(r.w01, f_lo(bv[q]), rl);
            rl = fmaf(r.w10, f_lo(cv[q]), rl);
            rl = fmaf(r.w11, f_lo(dv[q]), rl);
            float rh = r.w00 * f_hi(av[q]);
            rh = fmaf(r.w01, f_hi(bv[q]), rh);
            rh = fmaf(r.w10, f_hi(cv[q]), rh);
            rh = fmaf(r.w11, f_hi(dv[q]), rh);
            res[q] = __builtin_amdgcn_perm(__float_as_uint(rh),
                                           __float_as_uint(rl), 0x07060302u);
        }
        *(uint4*)(&s_S[buf][0] + sp * 64 + ((c8 ^ (sp & 7)) * 8)) =
            make_uint4(res[0], res[1], res[2], res[3]);
    };

    // ---------------- software-pipelined main loop ----------------
    dma_w(0, 0);
    {
        SampRegs r0 = sample_load(0);
        sample_store(r0, 0);
    }
    __syncthreads();

    for (int s = 0; s < NSTEP; ++s) {
        const int cur = s & 1;
        SampRegs rn;
        if (s < NSTEP - 1) {
            dma_w(s + 1, cur ^ 1);
            rn = sample_load(s + 1);      // corner loads in flight across MFMA
        }

        const unsigned short* Wb = &s_W[cur][0];
        const unsigned short* Sb = &s_S[cur][0];
        // explicit fragment reads (no duplicate LDS reads), then MFMA
        bf16x8 bf[2][2], af[2][4];
        #pragma unroll
        for (int kh = 0; kh < 2; ++kh) {
            const int pos = ((kh * 4 + kq) ^ sw) * 8;
            #pragma unroll
            for (int nt = 0; nt < 2; ++nt)
                bf[kh][nt] = *(const bf16x8*)(Sb + (nt * 16 + l15) * 64 + pos);
            #pragma unroll
            for (int mt = 0; mt < 4; ++mt)
                af[kh][mt] = *(const bf16x8*)(Wb + (oh * 64 + mt * 16 + l15) * 64 + pos);
        }
        #pragma unroll
        for (int kh = 0; kh < 2; ++kh)
            #pragma unroll
            for (int nt = 0; nt < 2; ++nt)
                #pragma unroll
                for (int mt = 0; mt < 4; ++mt)
                    acc[nt * 4 + mt] = __builtin_amdgcn_mfma_f32_16x16x32_bf16(
                        af[kh][mt], bf[kh][nt], acc[nt * 4 + mt], 0, 0, 0);

        if (s < NSTEP - 1) sample_store(rn, cur ^ 1);
        __syncthreads();   // fences next buffer's DMA + LDS stores
    }

    // ---- epilogue: ReLU + store. C/D: col=lane&15 -> px, row=(lane>>4)*4+r -> o ----
    #pragma unroll
    for (int nt = 0; nt < 2; ++nt) {
        const int px = w0 + nt * 16 + l15;
        #pragma unroll
        for (int mt = 0; mt < 4; ++mt) {
            const int obase = oh * 64 + mt * 16 + kq * 4;
            #pragma unroll
            for (int r = 0; r < 4; ++r) {
                out[(((size_t)b * COUT_ + obase + r) * H_ + h) * W_ + px] =
                    fmaxf(acc[nt * 4 + mt][r], 0.f);
            }
        }
    }
}

extern "C" void kernel_launch(void* const* d_in, const int* in_sizes, int n_in,
                              void* d_out, int out_size, void* d_ws, size_t ws_size,
                              hipStream_t stream) {
    const float* x     = (const float*)d_in[0];
    const float* y     = (const float*)d_in[1];
    const float* w_off = (const float*)d_in[2];
    const float* w_def = (const float*)d_in[3];
    float* out = (float*)d_out;

    unsigned short* xT = (unsigned short*)d_ws;                 // 8 MB
    unsigned short* wb = (unsigned short*)d_ws + 4194304;       // 1.18 MB

    xt_kernel<<<B_ * H_ * 2, 256, 0, stream>>>(x, xT);
    wt_kernel<<<(NSTEP * 16384) / 256, 256, 0, stream>>>(w_def, wb);
    dcn_kernel<<<512, 256, 0, stream>>>(xT, y, w_off, wb, out);
}

// Round 6
// 133.992 us; speedup vs baseline: 1.1014x; 1.0501x over previous
//
#include <hip/hip_runtime.h>
#include <cstddef>

#define B_    4
#define CIN_  256
#define COUT_ 256
#define H_    64
#define W_    64
#define KK_   9
#define G_    4
#define PAD_  1
#define TPX   64          // pixels per block = one full W row
#define NSL   18          // steps per block: 2 groups * 9 taps, K=64 each

typedef short bf16x8 __attribute__((ext_vector_type(8)));
typedef float f32x4  __attribute__((ext_vector_type(4)));
typedef __attribute__((address_space(1))) const unsigned int* gptr_t;
typedef __attribute__((address_space(3))) unsigned int*       lptr_t;

__device__ __forceinline__ unsigned short f2bf(float v) {
    unsigned int u = __float_as_uint(v);
    u += 0x7fffu + ((u >> 16) & 1u);
    return (unsigned short)(u >> 16);
}
__device__ __forceinline__ float f_lo(unsigned int u) { return __uint_as_float(u << 16); }
__device__ __forceinline__ float f_hi(unsigned int u) { return __uint_as_float(u & 0xffff0000u); }

// xT[b][h][w][c] (bf16, NHWC) <- x[b][c][h][w] (fp32)
__global__ __launch_bounds__(256) void xt_kernel(const float* __restrict__ x,
                                                 unsigned short* __restrict__ xT) {
    __shared__ unsigned short s[128][66];
    const int tid   = threadIdx.x;
    const int bh    = blockIdx.x >> 1;
    const int chalf = blockIdx.x & 1;
    const size_t src_base = ((size_t)(bh >> 6) * CIN_ + chalf * 128) * (H_ * W_) + (bh & 63) * W_;
    #pragma unroll 4
    for (int k = 0; k < 32; ++k) {
        int i = k * 256 + tid;
        int c = i >> 6, w = i & 63;
        s[c][w] = f2bf(x[src_base + (size_t)c * (H_ * W_) + w]);
    }
    __syncthreads();
    #pragma unroll 4
    for (int k = 0; k < 16; ++k) {
        int j  = k * 256 + tid;
        int c2 = (j & 63) * 2, w = j >> 6;
        unsigned int lo = s[c2][w], hi = s[c2 + 1][w];
        *(unsigned int*)(xT + ((size_t)bh * 64 + w) * 256 + chalf * 128 + c2) = lo | (hi << 16);
    }
}

// wb: 36 tiles [g][kk] of [o][pos*8+e] bf16, pos = j ^ (o&7), c = g*64 + j*8 + e
__global__ __launch_bounds__(256) void wt_kernel(const float* __restrict__ w,
                                                 unsigned short* __restrict__ wb) {
    int idx = blockIdx.x * 256 + threadIdx.x;    // 36*16384 exactly
    int e   = idx & 7;
    int pos = (idx >> 3) & 7;
    int o   = (idx >> 6) & 255;
    int t   = idx >> 14;                         // g*9 + kk
    int g   = t / 9, kk = t - g * 9;
    int j   = pos ^ (o & 7);
    int c   = g * 64 + j * 8 + e;
    wb[idx] = f2bf(w[(o * CIN_ + c) * KK_ + kk]);
}

// Main kernel: block = (bh row, khalf). Computes partial GEMM over K-half,
// writes fp32 partial (no relu) to part (= d_out for khalf 0, ws for khalf 1).
__global__ __launch_bounds__(512, 4) void dcn_kernel(
    const unsigned short* __restrict__ xT, const float* __restrict__ y,
    const float* __restrict__ w_off, const unsigned short* __restrict__ wb,
    float* __restrict__ part0, float* __restrict__ part1)
{
    __shared__ unsigned short s_W[COUT_ * 64];   // 32 KB
    __shared__ unsigned short s_S[TPX * 64];     //  8 KB

    const int tid = threadIdx.x;
    // XCD swizzle: all blocks on one XCD share (b, khalf) -> wb half + x slab in L2
    const int bid   = blockIdx.x;                // 512 blocks = 2/CU
    const int xcd   = bid & 7;
    const int b     = xcd >> 1;
    const int khalf = xcd & 1;
    const int h     = bid >> 3;

    // sampling mapping: thread -> (pixel sp, 8-ch chunk c8); 64*8 = 512 items
    const int sp = tid & 63;
    const int c8 = tid >> 6;

    const float yv0 = y[((b * 2 + 0) * H_ + h) * W_ + sp];
    const float yv1 = y[((b * 2 + 1) * H_ + h) * W_ + sp];

    // mfma mapping: 8 waves, wave = 64 outs (oh) x 32 px (pg)
    const int lane = tid & 63, wave = tid >> 6;
    const int pg  = wave & 1, oh = wave >> 1;
    const int l15 = lane & 15, kq = lane >> 4, sw = l15 & 7;

    f32x4 acc[8];   // [nt][mt] : 2 px-subtiles x 4 out-subtiles
    #pragma unroll
    for (int i = 0; i < 8; ++i) acc[i] = (f32x4){0.f, 0.f, 0.f, 0.f};

    const size_t xbase = (size_t)b * (H_ * W_ * 256) + c8 * 8;

    for (int sl = 0; sl < NSL; ++sl) {
        const int s  = khalf * NSL + sl;        // global step 0..35
        const int g  = khalf * 2 + sl / 9;
        const int kk = sl % 9;

        __syncthreads();   // all waves done reading s_W/s_S from prev step

        // ---- DMA W tile: 32 KB async global->LDS, 16 B/lane x 4 passes ----
        {
            const unsigned short* src = wb + (size_t)s * 16384;
            #pragma unroll
            for (int j = 0; j < 4; ++j) {
                const int off = (j * 512 + tid) * 8;
                __builtin_amdgcn_global_load_lds((gptr_t)(src + off),
                                                 (lptr_t)(s_W + off), 16, 0, 0);
            }
        }

        // ---- sample: 64 px x 64 ch, one (px, 8ch) item per thread ----
        {
            const float4 co = *(const float4*)(w_off + s * 4);   // uniform scalar load
            const float dy = fmaf(yv0, co.x, yv1 * co.y);
            const float dx = fmaf(yv0, co.z, yv1 * co.w);
            const float yc = (float)(h + (kk / 3) - PAD_) + dy;
            const float xc = (float)(sp + (kk % 3) - PAD_) + dx;
            const float yf = floorf(yc), xf = floorf(xc);
            const float wy = yc - yf,    wx = xc - xf;
            const int   yi = (int)yf,    xi = (int)xf;
            float w00 = (1.f - wy) * (1.f - wx);
            float w01 = (1.f - wy) * wx;
            float w10 = wy * (1.f - wx);
            float w11 = wy * wx;
            const bool y0ok = (yi >= 0) & (yi < H_);
            const bool y1ok = (yi >= -1) & (yi < H_ - 1);
            const bool x0ok = (xi >= 0) & (xi < W_);
            const bool x1ok = (xi >= -1) & (xi < W_ - 1);
            w00 = (y0ok & x0ok) ? w00 : 0.f;
            w01 = (y0ok & x1ok) ? w01 : 0.f;
            w10 = (y1ok & x0ok) ? w10 : 0.f;
            w11 = (y1ok & x1ok) ? w11 : 0.f;
            const int y0c = min(max(yi, 0), H_ - 1);
            const int y1c = min(max(yi + 1, 0), H_ - 1);
            const int x0c = min(max(xi, 0), W_ - 1);
            const int x1c = min(max(xi + 1, 0), W_ - 1);
            const unsigned short* xb = xT + xbase + g * 64;
            const uint4 A  = *(const uint4*)(xb + ((size_t)y0c * W_ + x0c) * 256);
            const uint4 Bv = *(const uint4*)(xb + ((size_t)y0c * W_ + x1c) * 256);
            const uint4 C  = *(const uint4*)(xb + ((size_t)y1c * W_ + x0c) * 256);
            const uint4 D  = *(const uint4*)(xb + ((size_t)y1c * W_ + x1c) * 256);
            const unsigned int av[4] = {A.x, A.y, A.z, A.w};
            const unsigned int bv[4] = {Bv.x, Bv.y, Bv.z, Bv.w};
            const unsigned int cv[4] = {C.x, C.y, C.z, C.w};
            const unsigned int dv[4] = {D.x, D.y, D.z, D.w};
            unsigned int res[4];
            #pragma unroll
            for (int q = 0; q < 4; ++q) {
                float rl = w00 * f_lo(av[q]);
                rl = fmaf(w01, f_lo(bv[q]), rl);
                rl = fmaf(w10, f_lo(cv[q]), rl);
                rl = fmaf(w11, f_lo(dv[q]), rl);
                float rh = w00 * f_hi(av[q]);
                rh = fmaf(w01, f_hi(bv[q]), rh);
                rh = fmaf(w10, f_hi(cv[q]), rh);
                rh = fmaf(w11, f_hi(dv[q]), rh);
                res[q] = __builtin_amdgcn_perm(__float_as_uint(rh),
                                               __float_as_uint(rl), 0x07060302u);
            }
            *(uint4*)(s_S + sp * 64 + ((c8 ^ (sp & 7)) * 8)) =
                make_uint4(res[0], res[1], res[2], res[3]);
        }

        __syncthreads();   // drains DMA + LDS stores

        // ---- MFMA: wave = [oh*64,+64) outs x [pg*32,+32) px, K=64 ----
        bf16x8 bf[2][2], af[2][4];
        #pragma unroll
        for (int kh = 0; kh < 2; ++kh) {
            const int pos = ((kh * 4 + kq) ^ sw) * 8;
            #pragma unroll
            for (int nt = 0; nt < 2; ++nt)
                bf[kh][nt] = *(const bf16x8*)(s_S + (pg * 32 + nt * 16 + l15) * 64 + pos);
            #pragma unroll
            for (int mt = 0; mt < 4; ++mt)
                af[kh][mt] = *(const bf16x8*)(s_W + (oh * 64 + mt * 16 + l15) * 64 + pos);
        }
        #pragma unroll
        for (int kh = 0; kh < 2; ++kh)
            #pragma unroll
            for (int nt = 0; nt < 2; ++nt)
                #pragma unroll
                for (int mt = 0; mt < 4; ++mt)
                    acc[nt * 4 + mt] = __builtin_amdgcn_mfma_f32_16x16x32_bf16(
                        af[kh][mt], bf[kh][nt], acc[nt * 4 + mt], 0, 0, 0);
    }

    // ---- epilogue: store fp32 partial (NO relu). C/D: col->px, row->o ----
    float* dst = khalf ? part1 : part0;
    #pragma unroll
    for (int nt = 0; nt < 2; ++nt) {
        const int px = pg * 32 + nt * 16 + l15;
        #pragma unroll
        for (int mt = 0; mt < 4; ++mt) {
            const int obase = oh * 64 + mt * 16 + kq * 4;
            #pragma unroll
            for (int r = 0; r < 4; ++r) {
                dst[(((size_t)b * COUT_ + obase + r) * H_ + h) * W_ + px] =
                    acc[nt * 4 + mt][r];
            }
        }
    }
}

// out = relu(out + part1), elementwise float4
__global__ __launch_bounds__(256) void red_kernel(const float4* __restrict__ p1,
                                                  float4* __restrict__ out) {
    const int i = blockIdx.x * 256 + threadIdx.x;
    float4 a = out[i];
    float4 b = p1[i];
    float4 r;
    r.x = fmaxf(a.x + b.x, 0.f);
    r.y = fmaxf(a.y + b.y, 0.f);
    r.z = fmaxf(a.z + b.z, 0.f);
    r.w = fmaxf(a.w + b.w, 0.f);
    out[i] = r;
}

extern "C" void kernel_launch(void* const* d_in, const int* in_sizes, int n_in,
                              void* d_out, int out_size, void* d_ws, size_t ws_size,
                              hipStream_t stream) {
    const float* x     = (const float*)d_in[0];
    const float* y     = (const float*)d_in[1];
    const float* w_off = (const float*)d_in[2];
    const float* w_def = (const float*)d_in[3];
    float* out = (float*)d_out;

    unsigned short* xT = (unsigned short*)d_ws;                      // 8 MB
    unsigned short* wb = (unsigned short*)d_ws + 4194304;            // 1.18 MB
    float* part1 = (float*)((char*)d_ws + 9568256);                  // 16.8 MB fp32 partial

    xt_kernel<<<B_ * H_ * 2, 256, 0, stream>>>(x, xT);
    wt_kernel<<<(36 * 16384) / 256, 256, 0, stream>>>(w_def, wb);
    dcn_kernel<<<512, 512, 0, stream>>>(xT, y, w_off, wb, out, part1);
    red_kernel<<<(B_ * COUT_ * H_ * W_) / 4 / 256, 256, 0, stream>>>(
        (const float4*)part1, (float4*)out);
}